// Round 8
// baseline (5788.913 us; speedup 1.0000x reference)
//
#include <hip/hip_runtime.h>

#define T_STEPS 256
#define BATCH   64
#define HID     1024
#define DIN     512
#define NCLS    1000
#define NBLK    192            // 64 L1 + 64 L2a + 64 L2b
#define PH_LAST 257            // phases p = 0..257
#define HSZ     (BATCH * HID)

typedef __attribute__((ext_vector_type(8))) short  short8;  // 8 bf16
typedef __attribute__((ext_vector_type(4))) float  f32x4;   // MFMA C/D

__device__ __forceinline__ unsigned short rne_bf16(float f) {
    unsigned int u = __builtin_bit_cast(unsigned int, f);
    u += 0x7FFFu + ((u >> 16) & 1u);
    return (unsigned short)(u >> 16);
}
__device__ __forceinline__ float bf16_to_f(unsigned short h) {
    unsigned int u = ((unsigned int)h) << 16;
    return __builtin_bit_cast(float, u);
}

#define MFMA(a, b, c) __builtin_amdgcn_mfma_f32_16x16x32_bf16((a), (b), (c), 0, 0, 0)

// Round-5/7-validated barrier: tid0-only release wb + relaxed counters +
// acquire inv. With redg gone, the release writeback now carries only
// ~1 MB/phase of h/u stores (round 7: 3 MB redg flushed+refetched = the
// whole 21 us/phase cost).
__device__ __forceinline__ void grid_bar(int* cnt, int* gen, int bid, int tid, int p) {
    __syncthreads();
    if (tid == 0) {
        __threadfence();   // release: L2 writeback (h/u stores -> L3)
        __hip_atomic_fetch_add(&cnt[(bid & 7) * 32], 1,
                               __ATOMIC_RELAXED, __HIP_MEMORY_SCOPE_AGENT);
        if (bid == 0) {
            const int target = NBLK * (p + 1);
            for (long it = 0; it < 2000000L; ++it) {
                int s = 0;
#pragma unroll
                for (int i = 0; i < 8; ++i)
                    s += __hip_atomic_load(&cnt[i * 32], __ATOMIC_RELAXED,
                                           __HIP_MEMORY_SCOPE_AGENT);
                if (s >= target) break;
                __builtin_amdgcn_s_sleep(1);
            }
            __threadfence();
            __hip_atomic_store(gen, p + 1, __ATOMIC_RELAXED, __HIP_MEMORY_SCOPE_AGENT);
        } else {
            for (long it = 0; it < 2000000L; ++it) {
                if (__hip_atomic_load(gen, __ATOMIC_RELAXED,
                                      __HIP_MEMORY_SCOPE_AGENT) >= p + 1)
                    break;
                __builtin_amdgcn_s_sleep(1);
            }
            __threadfence();   // acquire: invalidate L1/L2 before cross-XCD reads
        }
    }
    __syncthreads();
}

// ---------------------------------------------------------------------------
// Persistent MFMA RNN. 192 blocks x 256 threads (4 waves), 64 KB static LDS.
// Block: n16 x m64 x K1024, W hi+lo fully LDS-resident (staged once,
// lane-read-order layout -> 0 bank conflicts, verified round 7).
// KEY CHANGE vs round 7: wave w owns m-rows [16w,16w+16) with FULL K ->
// accumulator completes in-wave; no cross-wave reduction, no redg, no
// global scratch round-trip (round 7's entire 21 us/phase cost).
// Roles: bid<64:  L1  (W_hh0; h1_{p+1} = relu(xproj_p + Whh0 h1_p))
//        bid<128: L2a (W_ih1; u_p = Wih1 h1_p, fp32, no relu)
//        else:    L2b (W_hh1; h2_{p-1} = relu(u_{p-1} + Whh1 h2_{p-2}))
// Unique output ownership everywhere -> all stores plain.
// ---------------------------------------------------------------------------
__global__ __launch_bounds__(256)
void rnn_mfma(const float* __restrict__ xproj,
              const unsigned short* __restrict__ whh0h, const unsigned short* __restrict__ whh0l,
              const unsigned short* __restrict__ wih1h, const unsigned short* __restrict__ wih1l,
              const unsigned short* __restrict__ whh1h, const unsigned short* __restrict__ whh1l,
              unsigned short* h1hi, unsigned short* h1lo,
              unsigned short* h2hi, unsigned short* h2lo,
              float* ubuf, float* h2f, int* bar) {
    __shared__ short wlds[32 * 2 * 64 * 8];   // 64 KB: [kchunk32][hl2][lane64][8]

    const int bid  = blockIdx.x;
    const int role = bid >> 6;                // 0=L1, 1=L2a, 2=L2b
    const int n0   = (bid & 63) * 16;
    const int tid  = threadIdx.x;
    const int w    = tid >> 6;                // wave 0..3 -> m-tile
    const int lane = tid & 63;
    const int l15  = lane & 15;
    const int q    = lane >> 4;
    const int mw   = w * 16;

    const unsigned short* Wh = role == 0 ? whh0h : role == 1 ? wih1h : whh1h;
    const unsigned short* Wl = role == 0 ? whh0l : role == 1 ? wih1l : whh1l;

    // ---- one-time W staging: 4096 16B granules, lane-read-order layout ----
    for (int idx = tid; idx < 4096; idx += 256) {
        const int ln = idx & 63, hl = (idx >> 6) & 1, kc = idx >> 7;
        const unsigned short* src = (hl ? Wl : Wh) +
            (size_t)(n0 + (ln & 15)) * 1024 + kc * 32 + (ln >> 4) * 8;
        *(short8*)&wlds[((kc * 2 + hl) * 64 + ln) * 8] = *(const short8*)src;
    }
    __syncthreads();

    int* cnt = bar;
    int* gen = bar + 256;
    const size_t arow = (size_t)(mw + l15) * 1024 + q * 8;

    for (int p = 0; p <= PH_LAST; ++p) {
        const bool active = (role == 0) ? (p < T_STEPS)
                          : (role == 1) ? (p >= 1 && p <= T_STEPS)
                                        : (p >= 2);
        if (active) {
            const unsigned short* Ah = (role == 2 ? h2hi : h1hi) + (size_t)(p & 1) * HSZ;
            const unsigned short* Al = (role == 2 ? h2lo : h1lo) + (size_t)(p & 1) * HSZ;
            f32x4 acc = {};
#pragma unroll 8
            for (int kc = 0; kc < 32; ++kc) {
                const short8 wh = *(const short8*)&wlds[((kc * 2 + 0) * 64 + lane) * 8];
                const short8 wl = *(const short8*)&wlds[((kc * 2 + 1) * 64 + lane) * 8];
                const size_t ro = arow + kc * 32;
                const short8 ah = *(const short8*)(Ah + ro);
                const short8 al = *(const short8*)(Al + ro);
                acc = MFMA(ah, wh, acc);
                acc = MFMA(al, wh, acc);
                acc = MFMA(ah, wl, acc);
            }
            // C/D: n = l15, m = mw + q*4 + i
            if (role == 0) {
                const size_t ob = (size_t)((p + 1) & 1) * HSZ;
#pragma unroll
                for (int i = 0; i < 4; ++i) {
                    const size_t o = (size_t)(mw + q * 4 + i) * HID + n0 + l15;
                    const float v = fmaxf(acc[i] + xproj[(size_t)p * HSZ + o], 0.f);
                    const unsigned short g = rne_bf16(v);
                    h1hi[ob + o] = g;
                    h1lo[ob + o] = rne_bf16(v - bf16_to_f(g));
                }
            } else if (role == 1) {
                float* up = ubuf + (size_t)(p & 1) * HSZ;
#pragma unroll
                for (int i = 0; i < 4; ++i) {
                    const size_t o = (size_t)(mw + q * 4 + i) * HID + n0 + l15;
                    up[o] = acc[i];
                }
            } else {
                const size_t ob = (size_t)((p - 1) & 1) * HSZ;
                const float* up = ubuf + (size_t)((p - 1) & 1) * HSZ;
#pragma unroll
                for (int i = 0; i < 4; ++i) {
                    const size_t o = (size_t)(mw + q * 4 + i) * HID + n0 + l15;
                    const float v = fmaxf(acc[i] + up[o], 0.f);
                    const unsigned short g = rne_bf16(v);
                    h2hi[ob + o] = g;
                    h2lo[ob + o] = rne_bf16(v - bf16_to_f(g));
                    if (p == PH_LAST) h2f[o] = v;
                }
            }
        }
        grid_bar(cnt, gen, bid, tid, p);
    }
}

// ---------------------------------------------------------------------------
// Bulk x-projection: xproj[t][b][n] = sum_k x[b][t][k] * w_ih0[n][k].
// ---------------------------------------------------------------------------
__global__ __launch_bounds__(512)
void xproj_gemm(const float* __restrict__ x,
                const unsigned short* __restrict__ wh,
                const unsigned short* __restrict__ wl,
                float* __restrict__ xproj) {
    const int t    = blockIdx.x;
    const int nq   = blockIdx.y;
    const int w    = threadIdx.x >> 6;
    const int lane = threadIdx.x & 63;
    const int l15  = lane & 15;
    const int kq   = (lane >> 4) * 8;
    const int n0   = nq * 256 + w * 32;

    f32x4 acc[4][2] = {};
    for (int c = 0; c < 16; ++c) {
        const int k = c * 32 + kq;
        short8 wfh[2], wfl[2];
#pragma unroll
        for (int nt = 0; nt < 2; ++nt) {
            const size_t o = (size_t)(n0 + nt * 16 + l15) * DIN + k;
            wfh[nt] = *(const short8*)(wh + o);
            wfl[nt] = *(const short8*)(wl + o);
        }
#pragma unroll
        for (int mt = 0; mt < 4; ++mt) {
            const float* xr = x + ((size_t)(mt * 16 + l15) * T_STEPS + t) * DIN + k;
            float4 a0 = *(const float4*)xr;
            float4 a1 = *(const float4*)(xr + 4);
            float f[8] = {a0.x, a0.y, a0.z, a0.w, a1.x, a1.y, a1.z, a1.w};
            short8 ah, al;
#pragma unroll
            for (int i = 0; i < 8; ++i) {
                unsigned short h = rne_bf16(f[i]);
                ah[i] = (short)h;
                al[i] = (short)rne_bf16(f[i] - bf16_to_f(h));
            }
#pragma unroll
            for (int nt = 0; nt < 2; ++nt) {
                acc[mt][nt] = MFMA(ah, wfh[nt], acc[mt][nt]);
                acc[mt][nt] = MFMA(al, wfh[nt], acc[mt][nt]);
                acc[mt][nt] = MFMA(ah, wfl[nt], acc[mt][nt]);
            }
        }
    }
    float* op = xproj + (size_t)t * BATCH * HID;
#pragma unroll
    for (int mt = 0; mt < 4; ++mt)
#pragma unroll
        for (int nt = 0; nt < 2; ++nt)
#pragma unroll
            for (int i = 0; i < 4; ++i) {
                const int m = mt * 16 + (lane >> 4) * 4 + i;
                const int n = n0 + nt * 16 + l15;
                op[(size_t)m * HID + n] = acc[mt][nt][i];
            }
}

__global__ void split_w(const float* __restrict__ src,
                        unsigned short* __restrict__ hi,
                        unsigned short* __restrict__ lo, int n) {
    int i = blockIdx.x * 256 + threadIdx.x;
    if (i < n) {
        float v = src[i];
        unsigned short h = rne_bf16(v);
        hi[i] = h;
        lo[i] = rne_bf16(v - bf16_to_f(h));
    }
}

__global__ void zero_kernel(int* __restrict__ p, int n) {
    int i = blockIdx.x * 256 + threadIdx.x;
    if (i < n) p[i] = 0;
}

__global__ void fc_kernel(const float* __restrict__ h2,
                          const float* __restrict__ w_fc,
                          float* __restrict__ out) {
    __shared__ float hs[HID];
    const int b = blockIdx.x;
    for (int i = threadIdx.x; i < HID; i += 256) hs[i] = h2[(size_t)b * HID + i];
    __syncthreads();
    const int c = blockIdx.y * 256 + threadIdx.x;
    if (c < NCLS) {
        const float* w = w_fc + (size_t)c * HID;
        float s = 0.f;
        for (int k = 0; k < HID; k += 4) {
            float4 wv = *(const float4*)(w + k);
            s += wv.x * hs[k] + wv.y * hs[k + 1] + wv.z * hs[k + 2] + wv.w * hs[k + 3];
        }
        out[(size_t)b * NCLS + c] = s;
    }
}

extern "C" void kernel_launch(void* const* d_in, const int* in_sizes, int n_in,
                              void* d_out, int out_size, void* d_ws, size_t ws_size,
                              hipStream_t stream) {
    const float* x     = (const float*)d_in[0];
    const float* w_ih0 = (const float*)d_in[1];
    const float* w_hh0 = (const float*)d_in[2];
    const float* w_ih1 = (const float*)d_in[3];
    const float* w_hh1 = (const float*)d_in[4];
    const float* w_fc  = (const float*)d_in[5];
    float* out = (float*)d_out;

    char* ws = (char*)d_ws;
    size_t off = 0;
    auto alloc = [&](size_t bytes) { char* p = ws + off; off += bytes; return p; };
    float*          xproj = (float*)alloc((size_t)T_STEPS * BATCH * HID * 4);  // 64 MB
    unsigned short* wih0h = (unsigned short*)alloc((size_t)DIN * HID * 2);
    unsigned short* wih0l = (unsigned short*)alloc((size_t)DIN * HID * 2);
    unsigned short* whh0h = (unsigned short*)alloc((size_t)HID * HID * 2);
    unsigned short* whh0l = (unsigned short*)alloc((size_t)HID * HID * 2);
    unsigned short* wih1h = (unsigned short*)alloc((size_t)HID * HID * 2);
    unsigned short* wih1l = (unsigned short*)alloc((size_t)HID * HID * 2);
    unsigned short* whh1h = (unsigned short*)alloc((size_t)HID * HID * 2);
    unsigned short* whh1l = (unsigned short*)alloc((size_t)HID * HID * 2);
    unsigned short* h1hi  = (unsigned short*)alloc(2 * HSZ * 2);   // zeroed from here
    unsigned short* h1lo  = (unsigned short*)alloc(2 * HSZ * 2);
    unsigned short* h2hi  = (unsigned short*)alloc(2 * HSZ * 2);
    unsigned short* h2lo  = (unsigned short*)alloc(2 * HSZ * 2);
    float*          ubuf  = (float*)alloc(2 * HSZ * 4);
    float*          h2f   = (float*)alloc(HSZ * 4);
    int*            bar   = (int*)alloc(4096);

    // split weights to bf16 hi/lo
    split_w<<<(DIN * HID + 255) / 256, 256, 0, stream>>>(w_ih0, wih0h, wih0l, DIN * HID);
    split_w<<<(HID * HID + 255) / 256, 256, 0, stream>>>(w_hh0, whh0h, whh0l, HID * HID);
    split_w<<<(HID * HID + 255) / 256, 256, 0, stream>>>(w_ih1, wih1h, wih1l, HID * HID);
    split_w<<<(HID * HID + 255) / 256, 256, 0, stream>>>(w_hh1, whh1h, whh1l, HID * HID);

    // bulk x-projection (removes x from the recurrence critical path)
    xproj_gemm<<<dim3(T_STEPS, 4), 512, 0, stream>>>(x, wih0h, wih0l, xproj);

    // zero h states + ubuf + h2f + barrier (contiguous from h1hi)
    const int nzero = (4 * (2 * HSZ * 2) + 2 * HSZ * 4 + HSZ * 4 + 4096) / 4;
    zero_kernel<<<(nzero + 255) / 256, 256, 0, stream>>>((int*)h1hi, nzero);

    rnn_mfma<<<NBLK, 256, 0, stream>>>(xproj,
                                       whh0h, whh0l, wih1h, wih1l, whh1h, whh1l,
                                       h1hi, h1lo, h2hi, h2lo,
                                       ubuf, h2f, bar);

    fc_kernel<<<dim3(64, 4), 256, 0, stream>>>(h2f, w_fc, out);
}